// Round 3
// baseline (450.043 us; speedup 1.0000x reference)
//
#include <hip/hip_runtime.h>
#include <math.h>

#define NLEV 16
#define TBL  (1u << 19)
#define TMASK (TBL - 1u)

typedef _Float16 half8   __attribute__((ext_vector_type(8)));
typedef float    floatx4 __attribute__((ext_vector_type(4)));

struct ResParams { float resf[NLEV]; };

__device__ __forceinline__ float sigmoidf(float x) {
    return 1.0f / (1.0f + __expf(-x));
}

// XOR-swizzle for a [*][64] f16 buffer: 16-byte col-blocks permuted by row&7.
__device__ __forceinline__ int swz16(int row, int col) {      // row in [0,16)
    return row * 64 + ((((col >> 3) ^ (row & 7)) << 3) | (col & 7));
}
__device__ __forceinline__ int swz16_blk(int row, int blk) {  // blk = col/8
    return row * 64 + ((blk ^ (row & 7)) << 3);
}
__device__ __forceinline__ int swz64(int row, int col) {      // row in [0,64)
    return row * 64 + ((((col >> 3) ^ (row & 7)) << 3) | (col & 7));
}
__device__ __forceinline__ int swz64_blk(int row, int blk) {
    return row * 64 + ((blk ^ (row & 7)) << 3);
}

// ---------------------------------------------------------------------------
// Kernel 1: hash encoding. PRIMES[0]==1 => for even i0 the two x-corners are
// table entries h and h^1 (same 16B block) -> one dwordx4 serves both,
// cutting L2 lane-requests 8 -> 6 per (level, sample) on average.
// ---------------------------------------------------------------------------
__global__ __launch_bounds__(512) void k_hash(
    const float* __restrict__ t_starts, const float* __restrict__ t_ends,
    const float* __restrict__ rays_o,   const float* __restrict__ rays_d,
    const int*   __restrict__ ray_indices,
    const float* __restrict__ tables,
    const float* __restrict__ aabb,
    _Float16* __restrict__ encG, int n, ResParams rp)
{
    int i = blockIdx.x * 512 + threadIdx.x;
    if (i >= n) return;

    const int   ri = ray_indices[i];
    const float ts = t_starts[i], te = t_ends[i];
    const float tmid = 0.5f * (ts + te);

    const float ox = rays_o[ri * 3 + 0], oy = rays_o[ri * 3 + 1], oz = rays_o[ri * 3 + 2];
    const float dx = rays_d[ri * 3 + 0], dy = rays_d[ri * 3 + 1], dz = rays_d[ri * 3 + 2];

    const float a0 = aabb[0], a1 = aabb[1], a2 = aabb[2];
    const float b0 = aabb[3], b1 = aabb[4], b2 = aabb[5];

    const float xn0 = (ox + dx * tmid - a0) / (b0 - a0 + 1e-5f);
    const float xn1 = (oy + dy * tmid - a1) / (b1 - a1 + 1e-5f);
    const float xn2 = (oz + dz * tmid - a2) / (b2 - a2 + 1e-5f);

    const float x0 = fminf(fmaxf(xn0, 0.f), 1.f);
    const float x1 = fminf(fmaxf(xn1, 0.f), 1.f);
    const float x2 = fminf(fmaxf(xn2, 0.f), 1.f);

    union { _Float16 h[32]; uint4 q[4]; } ev;

    #pragma unroll
    for (int l = 0; l < NLEV; ++l) {
        const float resf = rp.resf[l];
        const float* __restrict__ tab = tables + (size_t)l * (size_t)(TBL * 2u);
        const float p0 = x0 * resf, p1 = x1 * resf, p2 = x2 * resf;
        const float fl0 = floorf(p0), fl1 = floorf(p1), fl2 = floorf(p2);
        const float f0 = p0 - fl0, f1 = p1 - fl1, f2 = p2 - fl2;
        const unsigned i0 = (unsigned)fl0, i1 = (unsigned)fl1, i2 = (unsigned)fl2;
        const unsigned hy0 = i1 * 2654435761u, hy1 = hy0 + 2654435761u;
        const unsigned hz0 = i2 * 805459861u,  hz1 = hz0 + 805459861u;
        const float g0 = 1.f - f0, g1 = 1.f - f1, g2 = 1.f - f2;

        const unsigned ryz[4] = { hy0 ^ hz0, hy0 ^ hz1, hy1 ^ hz0, hy1 ^ hz1 };
        const float    wyz[4] = { g1 * g2,   g1 * f2,   f1 * g2,   f1 * f2 };
        const bool odd = (i0 & 1u) != 0u;

        float e0 = 0.f, e1 = 0.f;
        #pragma unroll
        for (int c = 0; c < 4; ++c) {
            const unsigned h0 = (i0 ^ ryz[c]) & TMASK;
            float v0x, v0y, v1x, v1y;
            if (!odd) {
                // x-corners at h0 and h0^1: one 16B load
                const float4 v = *(const float4*)(tab + (h0 & ~1u) * 2u);
                if (h0 & 1u) { v0x = v.z; v0y = v.w; v1x = v.x; v1y = v.y; }
                else         { v0x = v.x; v0y = v.y; v1x = v.z; v1y = v.w; }
            } else {
                const unsigned h1 = ((i0 + 1u) ^ ryz[c]) & TMASK;
                const float2 va = *(const float2*)(tab + (size_t)h0 * 2u);
                const float2 vb = *(const float2*)(tab + (size_t)h1 * 2u);
                v0x = va.x; v0y = va.y; v1x = vb.x; v1y = vb.y;
            }
            const float wc = wyz[c];
            e0 += wc * (g0 * v0x + f0 * v1x);
            e1 += wc * (g0 * v0y + f0 * v1y);
        }
        ev.h[2 * l]     = (_Float16)(e0 * 1024.f);   // *1024: f16-normal range
        ev.h[2 * l + 1] = (_Float16)(e1 * 1024.f);
    }

    uint4* dst = (uint4*)(encG + (size_t)i * 32);
    dst[0] = ev.q[0]; dst[1] = ev.q[1]; dst[2] = ev.q[2]; dst[3] = ev.q[3];
}

// ---------------------------------------------------------------------------
// Kernel 2: fused MLP via MFMA f16. Block = 256 samples = 4 waves; each wave
// owns 64 rows. sHID is tile-private (GEMM2/4 read only the 16-row tile
// GEMM1/3 just wrote) -> 8 KB instead of 32 KB -> 4 blocks/CU.
// ---------------------------------------------------------------------------
__global__ __launch_bounds__(256) void k_mlp(
    const float* __restrict__ t_starts, const float* __restrict__ t_ends,
    const float* __restrict__ rays_o,   const float* __restrict__ rays_d,
    const int*   __restrict__ ray_indices,
    const float* __restrict__ bw0,  // [32,64]
    const float* __restrict__ bw1,  // [64,16]
    const float* __restrict__ hw0,  // [31,64]
    const float* __restrict__ hw1,  // [64,64]
    const float* __restrict__ hw2,  // [64,3]
    const float* __restrict__ aabb,
    const _Float16* __restrict__ encG,
    float4* __restrict__ srgb, int n)
{
    __shared__ _Float16 sHID[4 * 16 * 64];  // 8 KB: per-wave 16-row tile
    __shared__ _Float16 sSH [256 * 16];     // 8 KB
    __shared__ _Float16 sHB [256 * 16];     // 8 KB: h[1..15] + zero pad col 15
    __shared__ _Float16 sW0T[64 * 40];      // 5 KB: hw0^T, K padded 31->32
    __shared__ _Float16 sW1T[64 * 64];      // 8 KB, swizzled: hw1^T
    __shared__ float    sHW2[192];
    __shared__ float    sDT [256];          // sel ? (te-ts) : 0

    const int t     = threadIdx.x;
    const int gbase = blockIdx.x * 256;

    // ---- cooperative staging ----
    {
        const int s  = gbase + t;            // n % 256 == 0
        const int ri = ray_indices[s];
        const float ts = t_starts[s], te = t_ends[s];
        const float tmid = 0.5f * (ts + te);
        const float ox = rays_o[ri*3+0], oy = rays_o[ri*3+1], oz = rays_o[ri*3+2];
        const float dx = rays_d[ri*3+0], dy = rays_d[ri*3+1], dz = rays_d[ri*3+2];
        const float a0 = aabb[0], a1 = aabb[1], a2c = aabb[2];
        const float b0 = aabb[3], b1 = aabb[4], b2c = aabb[5];
        const float xn0 = (ox + dx*tmid - a0) / (b0 - a0 + 1e-5f);
        const float xn1 = (oy + dy*tmid - a1) / (b1 - a1 + 1e-5f);
        const float xn2 = (oz + dz*tmid - a2c) / (b2c - a2c + 1e-5f);
        const bool sel = (xn0 > 0.f) && (xn0 < 1.f) && (xn1 > 0.f) && (xn1 < 1.f)
                      && (xn2 > 0.f) && (xn2 < 1.f);
        sDT[t] = sel ? (te - ts) : 0.f;

        const float x = dx, y = dy, z = dz;
        const float x2 = x*x, y2 = y*y, z2 = z*z;
        const float xy = x*y, yz = y*z, xz = x*z;
        float shv[16];
        shv[0]  = 0.28209479177387814f;
        shv[1]  = -0.48860251190291987f * y;
        shv[2]  = 0.48860251190291987f * z;
        shv[3]  = -0.48860251190291987f * x;
        shv[4]  = 1.0925484305920792f * xy;
        shv[5]  = -1.0925484305920792f * yz;
        shv[6]  = 0.94617469575756f * z2 - 0.31539156525252005f;
        shv[7]  = -1.0925484305920792f * xz;
        shv[8]  = 0.5462742152960396f * (x2 - y2);
        shv[9]  = -0.5900435899266435f * y * (3.f*x2 - y2);
        shv[10] = 2.890611442640554f * xy * z;
        shv[11] = -0.4570457994644658f * y * (4.f*z2 - x2 - y2);
        shv[12] = 0.3731763325901154f * z * (2.f*z2 - 3.f*x2 - 3.f*y2);
        shv[13] = -0.4570457994644658f * x * (4.f*z2 - x2 - y2);
        shv[14] = 1.445305721320277f * z * (x2 - y2);
        shv[15] = -0.5900435899266435f * x * (x2 - 3.f*y2);
        #pragma unroll
        for (int k = 0; k < 16; ++k) sSH[t*16 + k] = (_Float16)shv[k];
    }
    {
        const int nidx = t & 63, g = t >> 6;
        #pragma unroll
        for (int i2 = 0; i2 < 8; ++i2) {            // hw0^T, zero pad k=31
            const int k = g*8 + i2;
            const float v = (k < 31) ? hw0[k*64 + nidx] : 0.f;
            sW0T[nidx*40 + k] = (_Float16)v;
        }
        #pragma unroll
        for (int i2 = 0; i2 < 16; ++i2) {           // hw1^T, swizzled
            const int k = g*16 + i2;
            sW1T[swz64(nidx, k)] = (_Float16)hw1[k*64 + nidx];
        }
        if (t < 192) sHW2[t] = hw2[t];
    }

    const int lane = t & 63, w = t >> 6;
    const int nn = lane & 15, quad = lane >> 4;
    half8 B1[4];                                    // bw0: K=32, N=64
    #pragma unroll
    for (int ct = 0; ct < 4; ++ct)
        #pragma unroll
        for (int j = 0; j < 8; ++j)
            B1[ct][j] = (_Float16)bw0[(quad*8 + j)*64 + ct*16 + nn];
    half8 B2[2];                                    // bw1: K=64, N=16
    #pragma unroll
    for (int ks = 0; ks < 2; ++ks)
        #pragma unroll
        for (int j = 0; j < 8; ++j)
            B2[ks][j] = (_Float16)bw1[(ks*32 + quad*8 + j)*16 + nn];

    __syncthreads();   // the only barrier

    const int rbase = w * 64;
    _Float16* myHID = &sHID[w * 1024];
    float sigv[16];

    // ---- GEMM1 (enc@bw0, relu) + GEMM2 (@bw1 -> h, sigma) ----
    #pragma unroll
    for (int rt = 0; rt < 4; ++rt) {
        const int mrow = rbase + rt*16 + nn;        // global row for A reads
        const int drow = rbase + rt*16 + quad*4;    // global row for epilogue

        half8 a1 = *(const half8*)(encG + (size_t)(gbase + mrow)*32 + quad*8);
        #pragma unroll
        for (int ct = 0; ct < 4; ++ct) {
            floatx4 acc = {0.f, 0.f, 0.f, 0.f};
            acc = __builtin_amdgcn_mfma_f32_16x16x32_f16(a1, B1[ct], acc, 0, 0, 0);
            #pragma unroll
            for (int r2 = 0; r2 < 4; ++r2)
                myHID[swz16(quad*4 + r2, ct*16 + nn)] = (_Float16)fmaxf(acc[r2], 0.f);
        }

        half8 a20 = *(const half8*)&myHID[swz16_blk(nn, 0*4 + quad)];
        half8 a21 = *(const half8*)&myHID[swz16_blk(nn, 1*4 + quad)];
        floatx4 acc = {0.f, 0.f, 0.f, 0.f};
        acc = __builtin_amdgcn_mfma_f32_16x16x32_f16(a20, B2[0], acc, 0, 0, 0);
        acc = __builtin_amdgcn_mfma_f32_16x16x32_f16(a21, B2[1], acc, 0, 0, 0);
        #pragma unroll
        for (int r2 = 0; r2 < 4; ++r2) {
            const float h = acc[r2] * (1.f / 1024.f);   // undo enc scale
            if (nn == 0) {
                sigv[rt*4 + r2] = __expf(h - 1.f) * sDT[drow + r2];
                sHB[(drow + r2)*16 + 15] = (_Float16)0.f;
            } else {
                sHB[(drow + r2)*16 + (nn - 1)] = (_Float16)h;
            }
        }
    }

    // ---- GEMM3 (hh@hw0, relu) + GEMM4 (@hw1, relu) + head_w2 reduction ----
    #pragma unroll
    for (int rt = 0; rt < 4; ++rt) {
        const int mrow = rbase + rt*16 + nn;
        const int drow = rbase + rt*16 + quad*4;

        half8 shf = *(const half8*)&sSH[mrow*16 + (quad & 1)*8];
        half8 hbf = *(const half8*)&sHB[mrow*16 + (quad & 1)*8];
        half8 a3f = (quad < 2) ? shf : hbf;

        #pragma unroll
        for (int ct = 0; ct < 4; ++ct) {
            half8 bf = *(const half8*)&sW0T[(ct*16 + nn)*40 + quad*8];
            floatx4 acc = {0.f, 0.f, 0.f, 0.f};
            acc = __builtin_amdgcn_mfma_f32_16x16x32_f16(a3f, bf, acc, 0, 0, 0);
            #pragma unroll
            for (int r2 = 0; r2 < 4; ++r2)
                myHID[swz16(quad*4 + r2, ct*16 + nn)] = (_Float16)fmaxf(acc[r2], 0.f);
        }

        float pr[4][3];
        #pragma unroll
        for (int r2 = 0; r2 < 4; ++r2) { pr[r2][0] = 0.f; pr[r2][1] = 0.f; pr[r2][2] = 0.f; }

        #pragma unroll
        for (int ct = 0; ct < 4; ++ct) {
            floatx4 acc = {0.f, 0.f, 0.f, 0.f};
            #pragma unroll
            for (int ks = 0; ks < 2; ++ks) {
                half8 af = *(const half8*)&myHID[swz16_blk(nn, ks*4 + quad)];
                half8 bf = *(const half8*)&sW1T[swz64_blk(ct*16 + nn, ks*4 + quad)];
                acc = __builtin_amdgcn_mfma_f32_16x16x32_f16(af, bf, acc, 0, 0, 0);
            }
            const float w0c = sHW2[(ct*16 + nn)*3 + 0];
            const float w1c = sHW2[(ct*16 + nn)*3 + 1];
            const float w2c = sHW2[(ct*16 + nn)*3 + 2];
            #pragma unroll
            for (int r2 = 0; r2 < 4; ++r2) {
                const float a3v = fmaxf(acc[r2], 0.f);
                pr[r2][0] = fmaf(a3v, w0c, pr[r2][0]);
                pr[r2][1] = fmaf(a3v, w1c, pr[r2][1]);
                pr[r2][2] = fmaf(a3v, w2c, pr[r2][2]);
            }
        }
        #pragma unroll
        for (int off = 1; off < 16; off <<= 1)
            #pragma unroll
            for (int r2 = 0; r2 < 4; ++r2) {
                pr[r2][0] += __shfl_xor(pr[r2][0], off, 64);
                pr[r2][1] += __shfl_xor(pr[r2][1], off, 64);
                pr[r2][2] += __shfl_xor(pr[r2][2], off, 64);
            }
        if (nn == 0) {
            #pragma unroll
            for (int r2 = 0; r2 < 4; ++r2) {
                float4 o;
                o.x = sigv[rt*4 + r2];
                o.y = sigmoidf(pr[r2][0]);
                o.z = sigmoidf(pr[r2][1]);
                o.w = sigmoidf(pr[r2][2]);
                srgb[gbase + drow + r2] = o;
            }
        }
    }
}

// ---------------------------------------------------------------------------
// Kernel 3: wave-per-ray compositing with shfl prefix scan.
// ---------------------------------------------------------------------------
__global__ __launch_bounds__(256) void k_render(
    const float* __restrict__ t_starts, const float* __restrict__ t_ends,
    const int*   __restrict__ ray_indices,
    const float4* __restrict__ srgb,
    float* __restrict__ out, int n_samples, int n_rays)
{
    const int wid  = (blockIdx.x * 256 + threadIdx.x) >> 6;
    const int lane = threadIdx.x & 63;
    if (wid >= n_rays) return;
    const int r = wid;

    int lo = 0, hi = n_samples;
    while (lo < hi) { int mid = (lo + hi) >> 1; if (ray_indices[mid] <  r) lo = mid + 1; else hi = mid; }
    const int start = lo;
    hi = n_samples;
    while (lo < hi) { int mid = (lo + hi) >> 1; if (ray_indices[mid] <= r) lo = mid + 1; else hi = mid; }
    const int end = lo;

    float S = 0.f, cr = 0.f, cg = 0.f, cb = 0.f, op = 0.f, dw = 0.f;
    for (int j0 = start; j0 < end; j0 += 64) {
        const int j = j0 + lane;
        float s = 0.f, R = 0.f, G = 0.f, B = 0.f, tm = 0.f;
        if (j < end) {
            const float4 v = srgb[j];
            s = v.x; R = v.y; G = v.z; B = v.w;
            tm = 0.5f * (t_starts[j] + t_ends[j]);
        }
        float incl = s;
        #pragma unroll
        for (int off = 1; off < 64; off <<= 1) {
            const float tv = __shfl_up(incl, off, 64);
            if (lane >= off) incl += tv;
        }
        const float excl  = incl - s;
        const float trans = __expf(-(S + excl));
        const float alpha = 1.f - __expf(-s);
        const float wgt   = trans * alpha;
        cr += wgt * R; cg += wgt * G; cb += wgt * B;
        op += wgt;     dw += wgt * tm;
        S += __shfl(incl, 63, 64);
    }
    #pragma unroll
    for (int off = 1; off < 64; off <<= 1) {
        cr += __shfl_xor(cr, off, 64);
        cg += __shfl_xor(cg, off, 64);
        cb += __shfl_xor(cb, off, 64);
        op += __shfl_xor(op, off, 64);
        dw += __shfl_xor(dw, off, 64);
    }
    if (lane == 0) {
        out[r*3 + 0] = cr;
        out[r*3 + 1] = cg;
        out[r*3 + 2] = cb;
        out[n_rays*3 + r] = op;
        out[n_rays*4 + r] = dw / fmaxf(op, 1.1920929e-7f);
    }
}

// ---------------------------------------------------------------------------
extern "C" void kernel_launch(void* const* d_in, const int* in_sizes, int n_in,
                              void* d_out, int out_size, void* d_ws, size_t ws_size,
                              hipStream_t stream)
{
    const float* t_starts    = (const float*)d_in[0];
    const float* t_ends      = (const float*)d_in[1];
    const float* rays_o      = (const float*)d_in[2];
    const float* rays_d      = (const float*)d_in[3];
    const int*   ray_indices = (const int*)  d_in[4];
    const float* tables      = (const float*)d_in[5];
    const float* bw0         = (const float*)d_in[6];
    const float* bw1         = (const float*)d_in[7];
    const float* hw0         = (const float*)d_in[8];
    const float* hw1         = (const float*)d_in[9];
    const float* hw2         = (const float*)d_in[10];
    const float* aabb        = (const float*)d_in[11];

    const int n      = in_sizes[0];        // 524288
    const int n_rays = in_sizes[2] / 3;    // 8192

    float*     out  = (float*)d_out;
    _Float16*  encG = (_Float16*)d_ws;                            // n*64 B
    float4*    srgb = (float4*)((char*)d_ws + (size_t)n * 64);    // n*16 B

    ResParams rp;
    const double scale = exp((log(4096.0) - log(16.0)) / 15.0);
    for (int l = 0; l < NLEV; ++l)
        rp.resf[l] = (float)floor(16.0 * pow(scale, (double)l));

    k_hash<<<(n + 511) / 512, 512, 0, stream>>>(
        t_starts, t_ends, rays_o, rays_d, ray_indices, tables, aabb, encG, n, rp);
    k_mlp<<<(n + 255) / 256, 256, 0, stream>>>(
        t_starts, t_ends, rays_o, rays_d, ray_indices, bw0, bw1, hw0, hw1, hw2,
        aabb, encG, srgb, n);
    k_render<<<(n_rays * 64 + 255) / 256, 256, 0, stream>>>(
        t_starts, t_ends, ray_indices, srgb, out, n, n_rays);
}

// Round 4
// 410.099 us; speedup vs baseline: 1.0974x; 1.0974x over previous
//
#include <hip/hip_runtime.h>
#include <math.h>

#define NLEV 16
#define TBL  (1u << 19)
#define TMASK (TBL - 1u)

typedef _Float16 half2v  __attribute__((ext_vector_type(2)));
typedef _Float16 half4   __attribute__((ext_vector_type(4)));
typedef _Float16 half8   __attribute__((ext_vector_type(8)));
typedef float    floatx4 __attribute__((ext_vector_type(4)));

struct ResParams { float resf[NLEV]; };

__device__ __forceinline__ float sigmoidf(float x) {
    return 1.0f / (1.0f + __expf(-x));
}

// XOR-swizzle for [*][64] f16 buffers: 16B col-blocks permuted by row&7.
__device__ __forceinline__ int swz64(int row, int col) {
    return row * 64 + ((((col >> 3) ^ (row & 7)) << 3) | (col & 7));
}
__device__ __forceinline__ int swz64_blk(int row, int blk) {
    return row * 64 + ((blk ^ (row & 7)) << 3);
}
__device__ __forceinline__ int swz16(int row, int col) {   // rows 0..15, 64 cols
    return row * 64 + ((((col >> 3) ^ (row & 7)) << 3) | (col & 7));
}
__device__ __forceinline__ int swz16_blk(int row, int blk) {
    return row * 64 + ((blk ^ (row & 7)) << 3);
}

// ---------------------------------------------------------------------------
// Kernel 0: tables f32 -> f16 (halves L2 working set for the gather kernel).
// ---------------------------------------------------------------------------
__global__ __launch_bounds__(256) void k_cvt(
    const float* __restrict__ src, _Float16* __restrict__ dst, int n4)
{
    const int i = blockIdx.x * 256 + threadIdx.x;
    if (i >= n4) return;
    const float4 v = ((const float4*)src)[i];
    half4 o; o[0] = (_Float16)v.x; o[1] = (_Float16)v.y;
    o[2] = (_Float16)v.z; o[3] = (_Float16)v.w;
    ((half4*)dst)[i] = o;
}

// ---------------------------------------------------------------------------
// Kernel 1 (f16 tables): hash encoding, 4 B per corner lookup.
// ---------------------------------------------------------------------------
__global__ __launch_bounds__(1024) void k_hash_f16(
    const float* __restrict__ t_starts, const float* __restrict__ t_ends,
    const float* __restrict__ rays_o,   const float* __restrict__ rays_d,
    const int*   __restrict__ ray_indices,
    const _Float16* __restrict__ tabh,
    const float* __restrict__ aabb,
    _Float16* __restrict__ encG, int n, ResParams rp)
{
    int i = blockIdx.x * 1024 + threadIdx.x;
    if (i >= n) return;

    const int   ri = ray_indices[i];
    const float ts = t_starts[i], te = t_ends[i];
    const float tmid = 0.5f * (ts + te);

    const float ox = rays_o[ri*3+0], oy = rays_o[ri*3+1], oz = rays_o[ri*3+2];
    const float dx = rays_d[ri*3+0], dy = rays_d[ri*3+1], dz = rays_d[ri*3+2];

    const float a0 = aabb[0], a1 = aabb[1], a2 = aabb[2];
    const float b0 = aabb[3], b1 = aabb[4], b2 = aabb[5];

    const float xn0 = (ox + dx*tmid - a0) / (b0 - a0 + 1e-5f);
    const float xn1 = (oy + dy*tmid - a1) / (b1 - a1 + 1e-5f);
    const float xn2 = (oz + dz*tmid - a2) / (b2 - a2 + 1e-5f);

    const float x0 = fminf(fmaxf(xn0, 0.f), 1.f);
    const float x1 = fminf(fmaxf(xn1, 0.f), 1.f);
    const float x2 = fminf(fmaxf(xn2, 0.f), 1.f);

    union { _Float16 h[32]; uint4 q[4]; } ev;

    #pragma unroll
    for (int l = 0; l < NLEV; ++l) {
        const float resf = rp.resf[l];
        const _Float16* __restrict__ tab = tabh + (size_t)l * (size_t)(TBL * 2u);
        const float p0 = x0 * resf, p1 = x1 * resf, p2 = x2 * resf;
        const float fl0 = floorf(p0), fl1 = floorf(p1), fl2 = floorf(p2);
        const float f0 = p0 - fl0, f1 = p1 - fl1, f2 = p2 - fl2;
        const unsigned i0 = (unsigned)fl0, i1 = (unsigned)fl1, i2 = (unsigned)fl2;
        const unsigned hx0 = i0,               hx1 = i0 + 1u;
        const unsigned hy0 = i1 * 2654435761u, hy1 = hy0 + 2654435761u;
        const unsigned hz0 = i2 * 805459861u,  hz1 = hz0 + 805459861u;
        const float g0 = 1.f - f0, g1 = 1.f - f1, g2 = 1.f - f2;
        float e0 = 0.f, e1 = 0.f;
        #pragma unroll
        for (int c = 0; c < 8; ++c) {       // corner bits: 4=x, 2=y, 1=z
            unsigned h = (((c & 4) ? hx1 : hx0) ^ ((c & 2) ? hy1 : hy0)
                        ^ ((c & 1) ? hz1 : hz0)) & TMASK;
            const float w = (((c & 4) ? f0 : g0) * ((c & 2) ? f1 : g1))
                          * ((c & 1) ? f2 : g2);
            const half2v tv = *(const half2v*)(tab + (size_t)h * 2u);
            e0 = fmaf((float)tv[0], w, e0);
            e1 = fmaf((float)tv[1], w, e1);
        }
        ev.h[2*l]   = (_Float16)(e0 * 1024.f);   // *1024: f16-normal range
        ev.h[2*l+1] = (_Float16)(e1 * 1024.f);
    }

    uint4* dst = (uint4*)(encG + (size_t)i * 32);
    dst[0] = ev.q[0]; dst[1] = ev.q[1]; dst[2] = ev.q[2]; dst[3] = ev.q[3];
}

// Fallback (f32 tables) if ws too small for the converted copy.
__global__ __launch_bounds__(256) void k_hash_f32(
    const float* __restrict__ t_starts, const float* __restrict__ t_ends,
    const float* __restrict__ rays_o,   const float* __restrict__ rays_d,
    const int*   __restrict__ ray_indices,
    const float* __restrict__ tables,
    const float* __restrict__ aabb,
    _Float16* __restrict__ encG, int n, ResParams rp)
{
    int i = blockIdx.x * 256 + threadIdx.x;
    if (i >= n) return;
    const int   ri = ray_indices[i];
    const float ts = t_starts[i], te = t_ends[i];
    const float tmid = 0.5f * (ts + te);
    const float ox = rays_o[ri*3+0], oy = rays_o[ri*3+1], oz = rays_o[ri*3+2];
    const float dx = rays_d[ri*3+0], dy = rays_d[ri*3+1], dz = rays_d[ri*3+2];
    const float a0 = aabb[0], a1 = aabb[1], a2 = aabb[2];
    const float b0 = aabb[3], b1 = aabb[4], b2 = aabb[5];
    const float xn0 = (ox + dx*tmid - a0) / (b0 - a0 + 1e-5f);
    const float xn1 = (oy + dy*tmid - a1) / (b1 - a1 + 1e-5f);
    const float xn2 = (oz + dz*tmid - a2) / (b2 - a2 + 1e-5f);
    const float x0 = fminf(fmaxf(xn0, 0.f), 1.f);
    const float x1 = fminf(fmaxf(xn1, 0.f), 1.f);
    const float x2 = fminf(fmaxf(xn2, 0.f), 1.f);
    union { _Float16 h[32]; uint4 q[4]; } ev;
    #pragma unroll
    for (int l = 0; l < NLEV; ++l) {
        const float resf = rp.resf[l];
        const float* __restrict__ tab = tables + (size_t)l * (size_t)(TBL * 2u);
        const float p0 = x0*resf, p1 = x1*resf, p2 = x2*resf;
        const float fl0 = floorf(p0), fl1 = floorf(p1), fl2 = floorf(p2);
        const float f0 = p0-fl0, f1 = p1-fl1, f2 = p2-fl2;
        const unsigned i0 = (unsigned)fl0, i1 = (unsigned)fl1, i2 = (unsigned)fl2;
        const unsigned hx0 = i0,               hx1 = i0 + 1u;
        const unsigned hy0 = i1 * 2654435761u, hy1 = hy0 + 2654435761u;
        const unsigned hz0 = i2 * 805459861u,  hz1 = hz0 + 805459861u;
        const float g0 = 1.f-f0, g1 = 1.f-f1, g2 = 1.f-f2;
        float e0 = 0.f, e1 = 0.f;
        #pragma unroll
        for (int c = 0; c < 8; ++c) {
            unsigned h = (((c&4)?hx1:hx0) ^ ((c&2)?hy1:hy0) ^ ((c&1)?hz1:hz0)) & TMASK;
            const float w = (((c&4)?f0:g0) * ((c&2)?f1:g1)) * ((c&1)?f2:g2);
            const float2 tv = *(const float2*)(tab + (size_t)h * 2u);
            e0 = fmaf(tv.x, w, e0);
            e1 = fmaf(tv.y, w, e1);
        }
        ev.h[2*l]   = (_Float16)(e0 * 1024.f);
        ev.h[2*l+1] = (_Float16)(e1 * 1024.f);
    }
    uint4* dst = (uint4*)(encG + (size_t)i * 32);
    dst[0] = ev.q[0]; dst[1] = ev.q[1]; dst[2] = ev.q[2]; dst[3] = ev.q[3];
}

// ---------------------------------------------------------------------------
// Kernel 2: fused MLP via MFMA f16, transposed-GEMM epilogues so accumulator
// quads pack into ds_write_b64 (4 consecutive dims of one sample).
// Block = 256 samples = 4 waves; one barrier.
// Layouts (gfx950 16x16x32): A[m=lane&15][k=quad*8+j], B[k][n=lane&15],
// D: row=quad*4+reg, col=lane&15.
// ---------------------------------------------------------------------------
__global__ __launch_bounds__(256) void k_mlp(
    const float* __restrict__ t_starts, const float* __restrict__ t_ends,
    const float* __restrict__ rays_o,   const float* __restrict__ rays_d,
    const int*   __restrict__ ray_indices,
    const float* __restrict__ bw0,  // [32,64]
    const float* __restrict__ bw1,  // [64,16]
    const float* __restrict__ hw0,  // [31,64]
    const float* __restrict__ hw1,  // [64,64]
    const float* __restrict__ hw2,  // [64,3]
    const float* __restrict__ aabb,
    const _Float16* __restrict__ encG,
    float4* __restrict__ srgb, int n)
{
    __shared__ _Float16 sT  [4][16 * 72];   // 9 KB: per-wave transpose buffer
    __shared__ _Float16 sSH [256 * 16];     // 8 KB
    __shared__ _Float16 sHB [256 * 16];     // 8 KB: h[1..15] + zero col 15
    __shared__ _Float16 sW0T[64 * 40];      // 5 KB: hw0^T, K 31->32 pad
    __shared__ _Float16 sW1T[64 * 64];      // 8 KB: hw1 B[k][n], swz64(n,k)
    __shared__ _Float16 sBW0T[64 * 32];     // 4 KB: bw0^T [hid][enc-k]
    __shared__ _Float16 sBW1T[16 * 64];     // 2 KB: bw1^T B-side, swz16(n,k)
    __shared__ float    sHW2[192];
    __shared__ float    sDT [256];

    const int t     = threadIdx.x;
    const int gbase = blockIdx.x * 256;

    // ---- cooperative staging ----
    {
        const int s  = gbase + t;            // n % 256 == 0
        const int ri = ray_indices[s];
        const float ts = t_starts[s], te = t_ends[s];
        const float tmid = 0.5f * (ts + te);
        const float ox = rays_o[ri*3+0], oy = rays_o[ri*3+1], oz = rays_o[ri*3+2];
        const float dx = rays_d[ri*3+0], dy = rays_d[ri*3+1], dz = rays_d[ri*3+2];
        const float a0 = aabb[0], a1 = aabb[1], a2c = aabb[2];
        const float b0 = aabb[3], b1 = aabb[4], b2c = aabb[5];
        const float xn0 = (ox + dx*tmid - a0) / (b0 - a0 + 1e-5f);
        const float xn1 = (oy + dy*tmid - a1) / (b1 - a1 + 1e-5f);
        const float xn2 = (oz + dz*tmid - a2c) / (b2c - a2c + 1e-5f);
        const bool sel = (xn0 > 0.f) && (xn0 < 1.f) && (xn1 > 0.f) && (xn1 < 1.f)
                      && (xn2 > 0.f) && (xn2 < 1.f);
        sDT[t] = sel ? (te - ts) : 0.f;

        const float x = dx, y = dy, z = dz;
        const float x2 = x*x, y2 = y*y, z2 = z*z;
        const float xy = x*y, yz = y*z, xz = x*z;
        float shv[16];
        shv[0]  = 0.28209479177387814f;
        shv[1]  = -0.48860251190291987f * y;
        shv[2]  = 0.48860251190291987f * z;
        shv[3]  = -0.48860251190291987f * x;
        shv[4]  = 1.0925484305920792f * xy;
        shv[5]  = -1.0925484305920792f * yz;
        shv[6]  = 0.94617469575756f * z2 - 0.31539156525252005f;
        shv[7]  = -1.0925484305920792f * xz;
        shv[8]  = 0.5462742152960396f * (x2 - y2);
        shv[9]  = -0.5900435899266435f * y * (3.f*x2 - y2);
        shv[10] = 2.890611442640554f * xy * z;
        shv[11] = -0.4570457994644658f * y * (4.f*z2 - x2 - y2);
        shv[12] = 0.3731763325901154f * z * (2.f*z2 - 3.f*x2 - 3.f*y2);
        shv[13] = -0.4570457994644658f * x * (4.f*z2 - x2 - y2);
        shv[14] = 1.445305721320277f * z * (x2 - y2);
        shv[15] = -0.5900435899266435f * x * (x2 - 3.f*y2);
        #pragma unroll
        for (int k4 = 0; k4 < 4; ++k4) {
            half4 p;
            #pragma unroll
            for (int j = 0; j < 4; ++j) p[j] = (_Float16)shv[k4*4 + j];
            *(half4*)&sSH[t*16 + k4*4] = p;
        }
    }
    {
        const int nidx = t & 63, g = t >> 6;
        #pragma unroll
        for (int i2 = 0; i2 < 8; ++i2) {            // hw0^T, zero pad k=31
            const int k = g*8 + i2;
            const float v = (k < 31) ? hw0[k*64 + nidx] : 0.f;
            sW0T[nidx*40 + k] = (_Float16)v;
        }
        #pragma unroll
        for (int i2 = 0; i2 < 16; ++i2) {           // hw1 as B[k][n]
            const int k = g*16 + i2;
            sW1T[swz64(nidx, k)] = (_Float16)hw1[k*64 + nidx];
        }
        #pragma unroll
        for (int i2 = 0; i2 < 8; ++i2) {            // bw0^T [hid n][enc k]
            const int k = g*8 + i2;                 // coalesced over nidx
            sBW0T[nidx*32 + k] = (_Float16)bw0[k*64 + nidx];
        }
        if (t < 192) sHW2[t] = hw2[t];
    }
    {
        const int nidx = t & 15, g = t >> 4;        // bw1^T B-side [h n][hid k]
        #pragma unroll
        for (int i2 = 0; i2 < 4; ++i2) {
            const int k = g*4 + i2;
            sBW1T[swz16(nidx, k)] = (_Float16)bw1[k*16 + nidx];
        }
    }

    const int lane = t & 63, w = t >> 6;
    const int nn = lane & 15, quad = lane >> 4;
    _Float16* myT = &sT[w][0];

    __syncthreads();   // the only barrier

    const int rbase = w * 64;
    float sigv[16];

    #pragma unroll
    for (int rt = 0; rt < 4; ++rt) {
        const int srow = rbase + rt*16;             // first sample of tile
        const int drow = srow + quad*4;             // D sample row (GEMM2/4)

        // ---- GEMM1 transposed: hid^T = bw0^T @ enc^T ----
        half8 bE = *(const half8*)(encG + (size_t)(gbase + srow + nn)*32 + quad*8);
        #pragma unroll
        for (int ct = 0; ct < 4; ++ct) {
            half8 aW = *(const half8*)&sBW0T[(ct*16 + nn)*32 + quad*8];
            floatx4 acc = {0.f, 0.f, 0.f, 0.f};
            acc = __builtin_amdgcn_mfma_f32_16x16x32_f16(aW, bE, acc, 0, 0, 0);
            half4 p;
            #pragma unroll
            for (int r2 = 0; r2 < 4; ++r2) p[r2] = (_Float16)fmaxf(acc[r2], 0.f);
            *(half4*)&myT[nn*72 + ct*16 + quad*4] = p;   // [sample][hid-dim]
        }

        // ---- GEMM2: h = hid @ bw1 ----
        {
            half8 a20 = *(const half8*)&myT[nn*72 +  0 + quad*8];
            half8 a21 = *(const half8*)&myT[nn*72 + 32 + quad*8];
            half8 b20 = *(const half8*)&sBW1T[swz16_blk(nn, quad)];
            half8 b21 = *(const half8*)&sBW1T[swz16_blk(nn, 4 + quad)];
            floatx4 acc = {0.f, 0.f, 0.f, 0.f};
            acc = __builtin_amdgcn_mfma_f32_16x16x32_f16(a20, b20, acc, 0, 0, 0);
            acc = __builtin_amdgcn_mfma_f32_16x16x32_f16(a21, b21, acc, 0, 0, 0);
            #pragma unroll
            for (int r2 = 0; r2 < 4; ++r2) {
                const float h = acc[r2] * (1.f / 1024.f);   // undo enc scale
                if (nn == 0) {
                    sigv[rt*4 + r2] = __expf(h - 1.f) * sDT[drow + r2];
                    sHB[(drow + r2)*16 + 15] = (_Float16)0.f;
                } else {
                    sHB[(drow + r2)*16 + (nn - 1)] = (_Float16)h;
                }
            }
        }

        // ---- GEMM3 transposed: a2^T = hw0^T @ hh^T ----
        half8 shf = *(const half8*)&sSH[(srow + nn)*16 + (quad & 1)*8];
        half8 hbf = *(const half8*)&sHB[(srow + nn)*16 + (quad & 1)*8];
        half8 a3f = (quad < 2) ? shf : hbf;          // B-frag: hh[sample nn][k]
        #pragma unroll
        for (int ct = 0; ct < 4; ++ct) {
            half8 aW = *(const half8*)&sW0T[(ct*16 + nn)*40 + quad*8];
            floatx4 acc = {0.f, 0.f, 0.f, 0.f};
            acc = __builtin_amdgcn_mfma_f32_16x16x32_f16(aW, a3f, acc, 0, 0, 0);
            half4 p;
            #pragma unroll
            for (int r2 = 0; r2 < 4; ++r2) p[r2] = (_Float16)fmaxf(acc[r2], 0.f);
            *(half4*)&myT[nn*72 + ct*16 + quad*4] = p;   // [sample][a2-dim]
        }

        // ---- GEMM4: a3 = a2 @ hw1, then head_w2 + shfl reduce ----
        half8 af0 = *(const half8*)&myT[nn*72 +  0 + quad*8];
        half8 af1 = *(const half8*)&myT[nn*72 + 32 + quad*8];
        float pr[4][3];
        #pragma unroll
        for (int r2 = 0; r2 < 4; ++r2) { pr[r2][0]=0.f; pr[r2][1]=0.f; pr[r2][2]=0.f; }
        #pragma unroll
        for (int ct = 0; ct < 4; ++ct) {
            half8 bf0 = *(const half8*)&sW1T[swz64_blk(ct*16 + nn, quad)];
            half8 bf1 = *(const half8*)&sW1T[swz64_blk(ct*16 + nn, 4 + quad)];
            floatx4 acc = {0.f, 0.f, 0.f, 0.f};
            acc = __builtin_amdgcn_mfma_f32_16x16x32_f16(af0, bf0, acc, 0, 0, 0);
            acc = __builtin_amdgcn_mfma_f32_16x16x32_f16(af1, bf1, acc, 0, 0, 0);
            const float w0c = sHW2[(ct*16 + nn)*3 + 0];
            const float w1c = sHW2[(ct*16 + nn)*3 + 1];
            const float w2c = sHW2[(ct*16 + nn)*3 + 2];
            #pragma unroll
            for (int r2 = 0; r2 < 4; ++r2) {
                const float a3v = fmaxf(acc[r2], 0.f);
                pr[r2][0] = fmaf(a3v, w0c, pr[r2][0]);
                pr[r2][1] = fmaf(a3v, w1c, pr[r2][1]);
                pr[r2][2] = fmaf(a3v, w2c, pr[r2][2]);
            }
        }
        #pragma unroll
        for (int off = 1; off < 16; off <<= 1)
            #pragma unroll
            for (int r2 = 0; r2 < 4; ++r2) {
                pr[r2][0] += __shfl_xor(pr[r2][0], off, 64);
                pr[r2][1] += __shfl_xor(pr[r2][1], off, 64);
                pr[r2][2] += __shfl_xor(pr[r2][2], off, 64);
            }
        if (nn == 0) {
            #pragma unroll
            for (int r2 = 0; r2 < 4; ++r2) {
                float4 o;
                o.x = sigv[rt*4 + r2];
                o.y = sigmoidf(pr[r2][0]);
                o.z = sigmoidf(pr[r2][1]);
                o.w = sigmoidf(pr[r2][2]);
                srgb[gbase + drow + r2] = o;
            }
        }
    }
}

// ---------------------------------------------------------------------------
// Kernel 3: wave-per-ray compositing with shfl prefix scan.
// ---------------------------------------------------------------------------
__global__ __launch_bounds__(256) void k_render(
    const float* __restrict__ t_starts, const float* __restrict__ t_ends,
    const int*   __restrict__ ray_indices,
    const float4* __restrict__ srgb,
    float* __restrict__ out, int n_samples, int n_rays)
{
    const int wid  = (blockIdx.x * 256 + threadIdx.x) >> 6;
    const int lane = threadIdx.x & 63;
    if (wid >= n_rays) return;
    const int r = wid;

    int lo = 0, hi = n_samples;
    while (lo < hi) { int mid = (lo + hi) >> 1; if (ray_indices[mid] <  r) lo = mid + 1; else hi = mid; }
    const int start = lo;
    hi = n_samples;
    while (lo < hi) { int mid = (lo + hi) >> 1; if (ray_indices[mid] <= r) lo = mid + 1; else hi = mid; }
    const int end = lo;

    float S = 0.f, cr = 0.f, cg = 0.f, cb = 0.f, op = 0.f, dw = 0.f;
    for (int j0 = start; j0 < end; j0 += 64) {
        const int j = j0 + lane;
        float s = 0.f, R = 0.f, G = 0.f, B = 0.f, tm = 0.f;
        if (j < end) {
            const float4 v = srgb[j];
            s = v.x; R = v.y; G = v.z; B = v.w;
            tm = 0.5f * (t_starts[j] + t_ends[j]);
        }
        float incl = s;
        #pragma unroll
        for (int off = 1; off < 64; off <<= 1) {
            const float tv = __shfl_up(incl, off, 64);
            if (lane >= off) incl += tv;
        }
        const float excl  = incl - s;
        const float trans = __expf(-(S + excl));
        const float alpha = 1.f - __expf(-s);
        const float wgt   = trans * alpha;
        cr += wgt * R; cg += wgt * G; cb += wgt * B;
        op += wgt;     dw += wgt * tm;
        S += __shfl(incl, 63, 64);
    }
    #pragma unroll
    for (int off = 1; off < 64; off <<= 1) {
        cr += __shfl_xor(cr, off, 64);
        cg += __shfl_xor(cg, off, 64);
        cb += __shfl_xor(cb, off, 64);
        op += __shfl_xor(op, off, 64);
        dw += __shfl_xor(dw, off, 64);
    }
    if (lane == 0) {
        out[r*3 + 0] = cr;
        out[r*3 + 1] = cg;
        out[r*3 + 2] = cb;
        out[n_rays*3 + r] = op;
        out[n_rays*4 + r] = dw / fmaxf(op, 1.1920929e-7f);
    }
}

// ---------------------------------------------------------------------------
extern "C" void kernel_launch(void* const* d_in, const int* in_sizes, int n_in,
                              void* d_out, int out_size, void* d_ws, size_t ws_size,
                              hipStream_t stream)
{
    const float* t_starts    = (const float*)d_in[0];
    const float* t_ends      = (const float*)d_in[1];
    const float* rays_o      = (const float*)d_in[2];
    const float* rays_d      = (const float*)d_in[3];
    const int*   ray_indices = (const int*)  d_in[4];
    const float* tables      = (const float*)d_in[5];
    const float* bw0         = (const float*)d_in[6];
    const float* bw1         = (const float*)d_in[7];
    const float* hw0         = (const float*)d_in[8];
    const float* hw1         = (const float*)d_in[9];
    const float* hw2         = (const float*)d_in[10];
    const float* aabb        = (const float*)d_in[11];

    const int n      = in_sizes[0];        // 524288
    const int n_rays = in_sizes[2] / 3;    // 8192
    const int tbl_n  = in_sizes[5];        // 16*T*2 floats

    float* out = (float*)d_out;
    char*  ws  = (char*)d_ws;

    const size_t tabh_bytes = (size_t)tbl_n * 2;           // f16 copy
    const size_t enc_bytes  = (size_t)n * 64;
    const size_t srgb_bytes = (size_t)n * 16;
    const bool   use_f16    = ws_size >= tabh_bytes + enc_bytes + srgb_bytes;

    ResParams rp;
    const double scale = exp((log(4096.0) - log(16.0)) / 15.0);
    for (int l = 0; l < NLEV; ++l)
        rp.resf[l] = (float)floor(16.0 * pow(scale, (double)l));

    _Float16* encG;
    float4*   srgb;
    if (use_f16) {
        _Float16* tabh = (_Float16*)ws;
        encG = (_Float16*)(ws + tabh_bytes);
        srgb = (float4*)(ws + tabh_bytes + enc_bytes);
        const int n4 = tbl_n / 4;
        k_cvt<<<(n4 + 255)/256, 256, 0, stream>>>(tables, tabh, n4);
        k_hash_f16<<<(n + 1023)/1024, 1024, 0, stream>>>(
            t_starts, t_ends, rays_o, rays_d, ray_indices, tabh, aabb, encG, n, rp);
    } else {
        encG = (_Float16*)ws;
        srgb = (float4*)(ws + enc_bytes);
        k_hash_f32<<<(n + 255)/256, 256, 0, stream>>>(
            t_starts, t_ends, rays_o, rays_d, ray_indices, tables, aabb, encG, n, rp);
    }

    k_mlp<<<(n + 255)/256, 256, 0, stream>>>(
        t_starts, t_ends, rays_o, rays_d, ray_indices, bw0, bw1, hw0, hw1, hw2,
        aabb, encG, srgb, n);
    k_render<<<(n_rays*64 + 255)/256, 256, 0, stream>>>(
        t_starts, t_ends, ray_indices, srgb, out, n, n_rays);
}

// Round 6
// 375.668 us; speedup vs baseline: 1.1980x; 1.0917x over previous
//
#include <hip/hip_runtime.h>
#include <math.h>

#define NLEV 16
#define TBL  (1u << 19)
#define TMASK (TBL - 1u)

typedef _Float16 half2v  __attribute__((ext_vector_type(2)));
typedef _Float16 half4   __attribute__((ext_vector_type(4)));
typedef _Float16 half8   __attribute__((ext_vector_type(8)));
typedef float    floatx4 __attribute__((ext_vector_type(4)));
typedef unsigned int uint4v __attribute__((ext_vector_type(4)));

struct ResParams { float resf[NLEV]; };

__device__ __forceinline__ float sigmoidf(float x) {
    return 1.0f / (1.0f + __expf(-x));
}

// XOR-swizzle for [*][64] f16 buffers: 16B col-blocks permuted by row&7.
__device__ __forceinline__ int swz64(int row, int col) {
    return row * 64 + ((((col >> 3) ^ (row & 7)) << 3) | (col & 7));
}
__device__ __forceinline__ int swz64_blk(int row, int blk) {
    return row * 64 + ((blk ^ (row & 7)) << 3);
}
__device__ __forceinline__ int swz16(int row, int col) {
    return row * 64 + ((((col >> 3) ^ (row & 7)) << 3) | (col & 7));
}
__device__ __forceinline__ int swz16_blk(int row, int blk) {
    return row * 64 + ((blk ^ (row & 7)) << 3);
}

// ---------------------------------------------------------------------------
// Kernel 0: tables f32 -> f16.
// ---------------------------------------------------------------------------
__global__ __launch_bounds__(256) void k_cvt(
    const float* __restrict__ src, _Float16* __restrict__ dst, int n4)
{
    const int i = blockIdx.x * 256 + threadIdx.x;
    if (i >= n4) return;
    const float4 v = ((const float4*)src)[i];
    half4 o; o[0] = (_Float16)v.x; o[1] = (_Float16)v.y;
    o[2] = (_Float16)v.z; o[3] = (_Float16)v.w;
    ((half4*)dst)[i] = o;
}

// ---------------------------------------------------------------------------
// Kernel 1: hash encoding, TWO samples per thread (i and i+n/2) with level
// loops interleaved -> 2x independent loads in flight per wave. Discriminates
// latency-bound vs L2-request-throughput-bound.
// ---------------------------------------------------------------------------
struct SampPos { float x0, x1, x2; };

__device__ __forceinline__ SampPos load_pos(
    int i, const float* __restrict__ t_starts, const float* __restrict__ t_ends,
    const float* __restrict__ rays_o, const float* __restrict__ rays_d,
    const int* __restrict__ ray_indices,
    float a0, float a1, float a2, float ib0, float ib1, float ib2)
{
    const int   ri = ray_indices[i];
    const float tmid = 0.5f * (t_starts[i] + t_ends[i]);
    const float xn0 = (rays_o[ri*3+0] + rays_d[ri*3+0]*tmid - a0) * ib0;
    const float xn1 = (rays_o[ri*3+1] + rays_d[ri*3+1]*tmid - a1) * ib1;
    const float xn2 = (rays_o[ri*3+2] + rays_d[ri*3+2]*tmid - a2) * ib2;
    SampPos p;
    p.x0 = fminf(fmaxf(xn0, 0.f), 1.f);
    p.x1 = fminf(fmaxf(xn1, 0.f), 1.f);
    p.x2 = fminf(fmaxf(xn2, 0.f), 1.f);
    return p;
}

__global__ __launch_bounds__(512) void k_hash2(
    const float* __restrict__ t_starts, const float* __restrict__ t_ends,
    const float* __restrict__ rays_o,   const float* __restrict__ rays_d,
    const int*   __restrict__ ray_indices,
    const _Float16* __restrict__ tabh,
    const float* __restrict__ aabb,
    _Float16* __restrict__ encG, int n, ResParams rp)
{
    const int nh = (n + 1) >> 1;
    const int iA = blockIdx.x * 512 + threadIdx.x;
    if (iA >= nh) return;
    int iB = iA + nh;
    const bool hasB = iB < n;
    if (!hasB) iB = iA;                 // mirror A; harmless duplicate work

    const float a0 = aabb[0], a1 = aabb[1], a2 = aabb[2];
    const float ib0 = 1.f / (aabb[3] - a0 + 1e-5f);
    const float ib1 = 1.f / (aabb[4] - a1 + 1e-5f);
    const float ib2 = 1.f / (aabb[5] - a2 + 1e-5f);

    const SampPos A = load_pos(iA, t_starts, t_ends, rays_o, rays_d, ray_indices,
                               a0, a1, a2, ib0, ib1, ib2);
    const SampPos B = load_pos(iB, t_starts, t_ends, rays_o, rays_d, ray_indices,
                               a0, a1, a2, ib0, ib1, ib2);

    union { _Float16 h[32]; uint4v q[4]; } evA, evB;

    #pragma unroll
    for (int l = 0; l < NLEV; ++l) {
        const float resf = rp.resf[l];
        const _Float16* __restrict__ tab = tabh + (size_t)l * (size_t)(TBL * 2u);

        // ---- sample A address/weight setup ----
        const float pA0 = A.x0*resf, pA1 = A.x1*resf, pA2 = A.x2*resf;
        const float flA0 = floorf(pA0), flA1 = floorf(pA1), flA2 = floorf(pA2);
        const float fA0 = pA0-flA0, fA1 = pA1-flA1, fA2 = pA2-flA2;
        const unsigned iA0 = (unsigned)flA0, iA1 = (unsigned)flA1, iA2 = (unsigned)flA2;
        const unsigned hAx0 = iA0,               hAx1 = iA0 + 1u;
        const unsigned hAy0 = iA1 * 2654435761u, hAy1 = hAy0 + 2654435761u;
        const unsigned hAz0 = iA2 * 805459861u,  hAz1 = hAz0 + 805459861u;
        const float gA0 = 1.f-fA0, gA1 = 1.f-fA1, gA2 = 1.f-fA2;

        // ---- sample B address/weight setup ----
        const float pB0 = B.x0*resf, pB1 = B.x1*resf, pB2 = B.x2*resf;
        const float flB0 = floorf(pB0), flB1 = floorf(pB1), flB2 = floorf(pB2);
        const float fB0 = pB0-flB0, fB1 = pB1-flB1, fB2 = pB2-flB2;
        const unsigned iB0 = (unsigned)flB0, iB1 = (unsigned)flB1, iB2 = (unsigned)flB2;
        const unsigned hBx0 = iB0,               hBx1 = iB0 + 1u;
        const unsigned hBy0 = iB1 * 2654435761u, hBy1 = hBy0 + 2654435761u;
        const unsigned hBz0 = iB2 * 805459861u,  hBz1 = hBz0 + 805459861u;
        const float gB0 = 1.f-fB0, gB1 = 1.f-fB1, gB2 = 1.f-fB2;

        // ---- issue all 16 loads, then accumulate ----
        half2v tvA[8], tvB[8];
        #pragma unroll
        for (int c = 0; c < 8; ++c) {
            const unsigned hA = (((c&4)?hAx1:hAx0) ^ ((c&2)?hAy1:hAy0)
                               ^ ((c&1)?hAz1:hAz0)) & TMASK;
            tvA[c] = *(const half2v*)(tab + (size_t)hA * 2u);
        }
        #pragma unroll
        for (int c = 0; c < 8; ++c) {
            const unsigned hB = (((c&4)?hBx1:hBx0) ^ ((c&2)?hBy1:hBy0)
                               ^ ((c&1)?hBz1:hBz0)) & TMASK;
            tvB[c] = *(const half2v*)(tab + (size_t)hB * 2u);
        }

        float eA0 = 0.f, eA1 = 0.f, eB0 = 0.f, eB1 = 0.f;
        #pragma unroll
        for (int c = 0; c < 8; ++c) {
            const float wA = (((c&4)?fA0:gA0) * ((c&2)?fA1:gA1)) * ((c&1)?fA2:gA2);
            eA0 = fmaf((float)tvA[c][0], wA, eA0);
            eA1 = fmaf((float)tvA[c][1], wA, eA1);
            const float wB = (((c&4)?fB0:gB0) * ((c&2)?fB1:gB1)) * ((c&1)?fB2:gB2);
            eB0 = fmaf((float)tvB[c][0], wB, eB0);
            eB1 = fmaf((float)tvB[c][1], wB, eB1);
        }
        evA.h[2*l]   = (_Float16)(eA0 * 1024.f);   // *1024: f16-normal range
        evA.h[2*l+1] = (_Float16)(eA1 * 1024.f);
        evB.h[2*l]   = (_Float16)(eB0 * 1024.f);
        evB.h[2*l+1] = (_Float16)(eB1 * 1024.f);
    }

    uint4v* dstA = (uint4v*)(encG + (size_t)iA * 32);
    #pragma unroll
    for (int q = 0; q < 4; ++q) __builtin_nontemporal_store(evA.q[q], dstA + q);
    if (hasB) {
        uint4v* dstB = (uint4v*)(encG + (size_t)iB * 32);
        #pragma unroll
        for (int q = 0; q < 4; ++q) __builtin_nontemporal_store(evB.q[q], dstB + q);
    }
}

// ---------------------------------------------------------------------------
// Kernel 2: fused MLP via MFMA f16 (unchanged from round 4).
// ---------------------------------------------------------------------------
__global__ __launch_bounds__(256) void k_mlp(
    const float* __restrict__ t_starts, const float* __restrict__ t_ends,
    const float* __restrict__ rays_o,   const float* __restrict__ rays_d,
    const int*   __restrict__ ray_indices,
    const float* __restrict__ bw0,  // [32,64]
    const float* __restrict__ bw1,  // [64,16]
    const float* __restrict__ hw0,  // [31,64]
    const float* __restrict__ hw1,  // [64,64]
    const float* __restrict__ hw2,  // [64,3]
    const float* __restrict__ aabb,
    const _Float16* __restrict__ encG,
    float4* __restrict__ srgb, int n)
{
    __shared__ _Float16 sT  [4][16 * 72];
    __shared__ _Float16 sSH [256 * 16];
    __shared__ _Float16 sHB [256 * 16];
    __shared__ _Float16 sW0T[64 * 40];
    __shared__ _Float16 sW1T[64 * 64];
    __shared__ _Float16 sBW0T[64 * 32];
    __shared__ _Float16 sBW1T[16 * 64];
    __shared__ float    sHW2[192];
    __shared__ float    sDT [256];

    const int t     = threadIdx.x;
    const int gbase = blockIdx.x * 256;

    {
        const int s  = gbase + t;            // n % 256 == 0
        const int ri = ray_indices[s];
        const float ts = t_starts[s], te = t_ends[s];
        const float tmid = 0.5f * (ts + te);
        const float ox = rays_o[ri*3+0], oy = rays_o[ri*3+1], oz = rays_o[ri*3+2];
        const float dx = rays_d[ri*3+0], dy = rays_d[ri*3+1], dz = rays_d[ri*3+2];
        const float a0 = aabb[0], a1 = aabb[1], a2c = aabb[2];
        const float b0 = aabb[3], b1 = aabb[4], b2c = aabb[5];
        const float xn0 = (ox + dx*tmid - a0) / (b0 - a0 + 1e-5f);
        const float xn1 = (oy + dy*tmid - a1) / (b1 - a1 + 1e-5f);
        const float xn2 = (oz + dz*tmid - a2c) / (b2c - a2c + 1e-5f);
        const bool sel = (xn0 > 0.f) && (xn0 < 1.f) && (xn1 > 0.f) && (xn1 < 1.f)
                      && (xn2 > 0.f) && (xn2 < 1.f);
        sDT[t] = sel ? (te - ts) : 0.f;

        const float x = dx, y = dy, z = dz;
        const float x2 = x*x, y2 = y*y, z2 = z*z;
        const float xy = x*y, yz = y*z, xz = x*z;
        float shv[16];
        shv[0]  = 0.28209479177387814f;
        shv[1]  = -0.48860251190291987f * y;
        shv[2]  = 0.48860251190291987f * z;
        shv[3]  = -0.48860251190291987f * x;
        shv[4]  = 1.0925484305920792f * xy;
        shv[5]  = -1.0925484305920792f * yz;
        shv[6]  = 0.94617469575756f * z2 - 0.31539156525252005f;
        shv[7]  = -1.0925484305920792f * xz;
        shv[8]  = 0.5462742152960396f * (x2 - y2);
        shv[9]  = -0.5900435899266435f * y * (3.f*x2 - y2);
        shv[10] = 2.890611442640554f * xy * z;
        shv[11] = -0.4570457994644658f * y * (4.f*z2 - x2 - y2);
        shv[12] = 0.3731763325901154f * z * (2.f*z2 - 3.f*x2 - 3.f*y2);
        shv[13] = -0.4570457994644658f * x * (4.f*z2 - x2 - y2);
        shv[14] = 1.445305721320277f * z * (x2 - y2);
        shv[15] = -0.5900435899266435f * x * (x2 - 3.f*y2);
        #pragma unroll
        for (int k4 = 0; k4 < 4; ++k4) {
            half4 p;
            #pragma unroll
            for (int j = 0; j < 4; ++j) p[j] = (_Float16)shv[k4*4 + j];
            *(half4*)&sSH[t*16 + k4*4] = p;
        }
    }
    {
        const int nidx = t & 63, g = t >> 6;
        #pragma unroll
        for (int i2 = 0; i2 < 8; ++i2) {
            const int k = g*8 + i2;
            const float v = (k < 31) ? hw0[k*64 + nidx] : 0.f;
            sW0T[nidx*40 + k] = (_Float16)v;
        }
        #pragma unroll
        for (int i2 = 0; i2 < 16; ++i2) {
            const int k = g*16 + i2;
            sW1T[swz64(nidx, k)] = (_Float16)hw1[k*64 + nidx];
        }
        #pragma unroll
        for (int i2 = 0; i2 < 8; ++i2) {
            const int k = g*8 + i2;
            sBW0T[nidx*32 + k] = (_Float16)bw0[k*64 + nidx];
        }
        if (t < 192) sHW2[t] = hw2[t];
    }
    {
        const int nidx = t & 15, g = t >> 4;
        #pragma unroll
        for (int i2 = 0; i2 < 4; ++i2) {
            const int k = g*4 + i2;
            sBW1T[swz16(nidx, k)] = (_Float16)bw1[k*16 + nidx];
        }
    }

    const int lane = t & 63, w = t >> 6;
    const int nn = lane & 15, quad = lane >> 4;
    _Float16* myT = &sT[w][0];

    __syncthreads();

    const int rbase = w * 64;
    float sigv[16];

    #pragma unroll
    for (int rt = 0; rt < 4; ++rt) {
        const int srow = rbase + rt*16;
        const int drow = srow + quad*4;

        half8 bE = *(const half8*)(encG + (size_t)(gbase + srow + nn)*32 + quad*8);
        #pragma unroll
        for (int ct = 0; ct < 4; ++ct) {
            half8 aW = *(const half8*)&sBW0T[(ct*16 + nn)*32 + quad*8];
            floatx4 acc = {0.f, 0.f, 0.f, 0.f};
            acc = __builtin_amdgcn_mfma_f32_16x16x32_f16(aW, bE, acc, 0, 0, 0);
            half4 p;
            #pragma unroll
            for (int r2 = 0; r2 < 4; ++r2) p[r2] = (_Float16)fmaxf(acc[r2], 0.f);
            *(half4*)&myT[nn*72 + ct*16 + quad*4] = p;
        }

        {
            half8 a20 = *(const half8*)&myT[nn*72 +  0 + quad*8];
            half8 a21 = *(const half8*)&myT[nn*72 + 32 + quad*8];
            half8 b20 = *(const half8*)&sBW1T[swz16_blk(nn, quad)];
            half8 b21 = *(const half8*)&sBW1T[swz16_blk(nn, 4 + quad)];
            floatx4 acc = {0.f, 0.f, 0.f, 0.f};
            acc = __builtin_amdgcn_mfma_f32_16x16x32_f16(a20, b20, acc, 0, 0, 0);
            acc = __builtin_amdgcn_mfma_f32_16x16x32_f16(a21, b21, acc, 0, 0, 0);
            #pragma unroll
            for (int r2 = 0; r2 < 4; ++r2) {
                const float h = acc[r2] * (1.f / 1024.f);
                if (nn == 0) {
                    sigv[rt*4 + r2] = __expf(h - 1.f) * sDT[drow + r2];
                    sHB[(drow + r2)*16 + 15] = (_Float16)0.f;
                } else {
                    sHB[(drow + r2)*16 + (nn - 1)] = (_Float16)h;
                }
            }
        }

        half8 shf = *(const half8*)&sSH[(srow + nn)*16 + (quad & 1)*8];
        half8 hbf = *(const half8*)&sHB[(srow + nn)*16 + (quad & 1)*8];
        half8 a3f = (quad < 2) ? shf : hbf;
        #pragma unroll
        for (int ct = 0; ct < 4; ++ct) {
            half8 aW = *(const half8*)&sW0T[(ct*16 + nn)*40 + quad*8];
            floatx4 acc = {0.f, 0.f, 0.f, 0.f};
            acc = __builtin_amdgcn_mfma_f32_16x16x32_f16(aW, a3f, acc, 0, 0, 0);
            half4 p;
            #pragma unroll
            for (int r2 = 0; r2 < 4; ++r2) p[r2] = (_Float16)fmaxf(acc[r2], 0.f);
            *(half4*)&myT[nn*72 + ct*16 + quad*4] = p;
        }

        half8 af0 = *(const half8*)&myT[nn*72 +  0 + quad*8];
        half8 af1 = *(const half8*)&myT[nn*72 + 32 + quad*8];
        float pr[4][3];
        #pragma unroll
        for (int r2 = 0; r2 < 4; ++r2) { pr[r2][0]=0.f; pr[r2][1]=0.f; pr[r2][2]=0.f; }
        #pragma unroll
        for (int ct = 0; ct < 4; ++ct) {
            half8 bf0 = *(const half8*)&sW1T[swz64_blk(ct*16 + nn, quad)];
            half8 bf1 = *(const half8*)&sW1T[swz64_blk(ct*16 + nn, 4 + quad)];
            floatx4 acc = {0.f, 0.f, 0.f, 0.f};
            acc = __builtin_amdgcn_mfma_f32_16x16x32_f16(af0, bf0, acc, 0, 0, 0);
            acc = __builtin_amdgcn_mfma_f32_16x16x32_f16(af1, bf1, acc, 0, 0, 0);
            const float w0c = sHW2[(ct*16 + nn)*3 + 0];
            const float w1c = sHW2[(ct*16 + nn)*3 + 1];
            const float w2c = sHW2[(ct*16 + nn)*3 + 2];
            #pragma unroll
            for (int r2 = 0; r2 < 4; ++r2) {
                const float a3v = fmaxf(acc[r2], 0.f);
                pr[r2][0] = fmaf(a3v, w0c, pr[r2][0]);
                pr[r2][1] = fmaf(a3v, w1c, pr[r2][1]);
                pr[r2][2] = fmaf(a3v, w2c, pr[r2][2]);
            }
        }
        #pragma unroll
        for (int off = 1; off < 16; off <<= 1)
            #pragma unroll
            for (int r2 = 0; r2 < 4; ++r2) {
                pr[r2][0] += __shfl_xor(pr[r2][0], off, 64);
                pr[r2][1] += __shfl_xor(pr[r2][1], off, 64);
                pr[r2][2] += __shfl_xor(pr[r2][2], off, 64);
            }
        if (nn == 0) {
            #pragma unroll
            for (int r2 = 0; r2 < 4; ++r2) {
                float4 o;
                o.x = sigv[rt*4 + r2];
                o.y = sigmoidf(pr[r2][0]);
                o.z = sigmoidf(pr[r2][1]);
                o.w = sigmoidf(pr[r2][2]);
                srgb[gbase + drow + r2] = o;
            }
        }
    }
}

// ---------------------------------------------------------------------------
// Kernel 3: wave-per-ray compositing with shfl prefix scan (unchanged).
// ---------------------------------------------------------------------------
__global__ __launch_bounds__(256) void k_render(
    const float* __restrict__ t_starts, const float* __restrict__ t_ends,
    const int*   __restrict__ ray_indices,
    const float4* __restrict__ srgb,
    float* __restrict__ out, int n_samples, int n_rays)
{
    const int wid  = (blockIdx.x * 256 + threadIdx.x) >> 6;
    const int lane = threadIdx.x & 63;
    if (wid >= n_rays) return;
    const int r = wid;

    int lo = 0, hi = n_samples;
    while (lo < hi) { int mid = (lo + hi) >> 1; if (ray_indices[mid] <  r) lo = mid + 1; else hi = mid; }
    const int start = lo;
    hi = n_samples;
    while (lo < hi) { int mid = (lo + hi) >> 1; if (ray_indices[mid] <= r) lo = mid + 1; else hi = mid; }
    const int end = lo;

    float S = 0.f, cr = 0.f, cg = 0.f, cb = 0.f, op = 0.f, dw = 0.f;
    for (int j0 = start; j0 < end; j0 += 64) {
        const int j = j0 + lane;
        float s = 0.f, R = 0.f, G = 0.f, B = 0.f, tm = 0.f;
        if (j < end) {
            const float4 v = srgb[j];
            s = v.x; R = v.y; G = v.z; B = v.w;
            tm = 0.5f * (t_starts[j] + t_ends[j]);
        }
        float incl = s;
        #pragma unroll
        for (int off = 1; off < 64; off <<= 1) {
            const float tv = __shfl_up(incl, off, 64);
            if (lane >= off) incl += tv;
        }
        const float excl  = incl - s;
        const float trans = __expf(-(S + excl));
        const float alpha = 1.f - __expf(-s);
        const float wgt   = trans * alpha;
        cr += wgt * R; cg += wgt * G; cb += wgt * B;
        op += wgt;     dw += wgt * tm;
        S += __shfl(incl, 63, 64);
    }
    #pragma unroll
    for (int off = 1; off < 64; off <<= 1) {
        cr += __shfl_xor(cr, off, 64);
        cg += __shfl_xor(cg, off, 64);
        cb += __shfl_xor(cb, off, 64);
        op += __shfl_xor(op, off, 64);
        dw += __shfl_xor(dw, off, 64);
    }
    if (lane == 0) {
        out[r*3 + 0] = cr;
        out[r*3 + 1] = cg;
        out[r*3 + 2] = cb;
        out[n_rays*3 + r] = op;
        out[n_rays*4 + r] = dw / fmaxf(op, 1.1920929e-7f);
    }
}

// ---------------------------------------------------------------------------
extern "C" void kernel_launch(void* const* d_in, const int* in_sizes, int n_in,
                              void* d_out, int out_size, void* d_ws, size_t ws_size,
                              hipStream_t stream)
{
    const float* t_starts    = (const float*)d_in[0];
    const float* t_ends      = (const float*)d_in[1];
    const float* rays_o      = (const float*)d_in[2];
    const float* rays_d      = (const float*)d_in[3];
    const int*   ray_indices = (const int*)  d_in[4];
    const float* tables      = (const float*)d_in[5];
    const float* bw0         = (const float*)d_in[6];
    const float* bw1         = (const float*)d_in[7];
    const float* hw0         = (const float*)d_in[8];
    const float* hw1         = (const float*)d_in[9];
    const float* hw2         = (const float*)d_in[10];
    const float* aabb        = (const float*)d_in[11];

    const int n      = in_sizes[0];        // 524288
    const int n_rays = in_sizes[2] / 3;    // 8192
    const int tbl_n  = in_sizes[5];        // 16*T*2 floats

    float* out = (float*)d_out;
    char*  ws  = (char*)d_ws;

    const size_t tabh_bytes = (size_t)tbl_n * 2;
    const size_t enc_bytes  = (size_t)n * 64;

    ResParams rp;
    const double scale = exp((log(4096.0) - log(16.0)) / 15.0);
    for (int l = 0; l < NLEV; ++l)
        rp.resf[l] = (float)floor(16.0 * pow(scale, (double)l));

    _Float16* tabh = (_Float16*)ws;
    _Float16* encG = (_Float16*)(ws + tabh_bytes);
    float4*   srgb = (float4*)(ws + tabh_bytes + enc_bytes);

    const int n4 = tbl_n / 4;
    k_cvt<<<(n4 + 255)/256, 256, 0, stream>>>(tables, tabh, n4);

    const int nh = (n + 1) >> 1;
    k_hash2<<<(nh + 511)/512, 512, 0, stream>>>(
        t_starts, t_ends, rays_o, rays_d, ray_indices, tabh, aabb, encG, n, rp);

    k_mlp<<<(n + 255)/256, 256, 0, stream>>>(
        t_starts, t_ends, rays_o, rays_d, ray_indices, bw0, bw1, hw0, hw1, hw2,
        aabb, encG, srgb, n);
    k_render<<<(n_rays*64 + 255)/256, 256, 0, stream>>>(
        t_starts, t_ends, ray_indices, srgb, out, n, n_rays);
}

// Round 7
// 335.902 us; speedup vs baseline: 1.3398x; 1.1184x over previous
//
#include <hip/hip_runtime.h>
#include <math.h>

#define NLEV 16
#define TBL  (1u << 19)
#define TMASK (TBL - 1u)

typedef _Float16 half2v  __attribute__((ext_vector_type(2)));
typedef _Float16 half4   __attribute__((ext_vector_type(4)));
typedef _Float16 half8   __attribute__((ext_vector_type(8)));
typedef float    floatx4 __attribute__((ext_vector_type(4)));
typedef unsigned int uint2v __attribute__((ext_vector_type(2)));
typedef unsigned int uint4v __attribute__((ext_vector_type(4)));

struct ResParams { float resf[NLEV]; };

__device__ __forceinline__ float sigmoidf(float x) {
    return 1.0f / (1.0f + __expf(-x));
}

__device__ __forceinline__ float2 unpack_h2(unsigned u) {
    union { unsigned u; half2v h; } c; c.u = u;
    return make_float2((float)c.h[0], (float)c.h[1]);
}

// XOR-swizzle for [*][64] f16 buffers: 16B col-blocks permuted by row&7.
__device__ __forceinline__ int swz64(int row, int col) {
    return row * 64 + ((((col >> 3) ^ (row & 7)) << 3) | (col & 7));
}
__device__ __forceinline__ int swz64_blk(int row, int blk) {
    return row * 64 + ((blk ^ (row & 7)) << 3);
}
__device__ __forceinline__ int swz16(int row, int col) {
    return row * 64 + ((((col >> 3) ^ (row & 7)) << 3) | (col & 7));
}
__device__ __forceinline__ int swz16_blk(int row, int blk) {
    return row * 64 + ((blk ^ (row & 7)) << 3);
}

// ---------------------------------------------------------------------------
// Kernel 0: tables f32 -> f16.
// ---------------------------------------------------------------------------
__global__ __launch_bounds__(256) void k_cvt(
    const float* __restrict__ src, _Float16* __restrict__ dst, int n4)
{
    const int i = blockIdx.x * 256 + threadIdx.x;
    if (i >= n4) return;
    const float4 v = ((const float4*)src)[i];
    half4 o; o[0] = (_Float16)v.x; o[1] = (_Float16)v.y;
    o[2] = (_Float16)v.z; o[3] = (_Float16)v.w;
    ((half4*)dst)[i] = o;
}

// ---------------------------------------------------------------------------
// Kernel 1: hash encoding, 2 samples/thread (ILP) + x-pair 8B loads.
// PRIMES[0]==1: even i0 -> x-corners are table entries h and h^1, one aligned
// dwordx2 serves both. Cuts L2 lane-requests 8 -> 6 per (sample,level) avg.
// ---------------------------------------------------------------------------
struct SampPos { float x0, x1, x2; };

__device__ __forceinline__ SampPos load_pos(
    int i, const float* __restrict__ t_starts, const float* __restrict__ t_ends,
    const float* __restrict__ rays_o, const float* __restrict__ rays_d,
    const int* __restrict__ ray_indices,
    float a0, float a1, float a2, float ib0, float ib1, float ib2)
{
    const int   ri = ray_indices[i];
    const float tmid = 0.5f * (t_starts[i] + t_ends[i]);
    const float xn0 = (rays_o[ri*3+0] + rays_d[ri*3+0]*tmid - a0) * ib0;
    const float xn1 = (rays_o[ri*3+1] + rays_d[ri*3+1]*tmid - a1) * ib1;
    const float xn2 = (rays_o[ri*3+2] + rays_d[ri*3+2]*tmid - a2) * ib2;
    SampPos p;
    p.x0 = fminf(fmaxf(xn0, 0.f), 1.f);
    p.x1 = fminf(fmaxf(xn1, 0.f), 1.f);
    p.x2 = fminf(fmaxf(xn2, 0.f), 1.f);
    return p;
}

// Gather the 8 corner entries for one (sample, level). v0[c]/v1[c] are the
// f16x2 entries for the x0/x1 corner of yz-combo c.
__device__ __forceinline__ void corner_gather(
    const _Float16* __restrict__ tab, unsigned i0,
    const unsigned ryz[4], unsigned v0[4], unsigned v1[4])
{
    if (!(i0 & 1u)) {            // even: pair {h, h^1} in one 8B block
        #pragma unroll
        for (int c = 0; c < 4; ++c) {
            const unsigned lo = (i0 ^ ryz[c]) & TMASK;
            const uint2v p = *(const uint2v*)(tab + (size_t)(lo & ~1u) * 2u);
            const unsigned sw = lo & 1u;
            v0[c] = sw ? p.y : p.x;
            v1[c] = sw ? p.x : p.y;
        }
    } else {                     // odd: two independent 4B loads
        #pragma unroll
        for (int c = 0; c < 4; ++c) {
            const unsigned lo = (i0        ^ ryz[c]) & TMASK;
            const unsigned hi = ((i0 + 1u) ^ ryz[c]) & TMASK;
            v0[c] = *(const unsigned*)(tab + (size_t)lo * 2u);
            v1[c] = *(const unsigned*)(tab + (size_t)hi * 2u);
        }
    }
}

__global__ __launch_bounds__(256) void k_hash2(
    const float* __restrict__ t_starts, const float* __restrict__ t_ends,
    const float* __restrict__ rays_o,   const float* __restrict__ rays_d,
    const int*   __restrict__ ray_indices,
    const _Float16* __restrict__ tabh,
    const float* __restrict__ aabb,
    _Float16* __restrict__ encG, int n, ResParams rp)
{
    const int nh = (n + 1) >> 1;
    const int iA = blockIdx.x * 256 + threadIdx.x;
    if (iA >= nh) return;
    int iB = iA + nh;
    const bool hasB = iB < n;
    if (!hasB) iB = iA;

    const float a0 = aabb[0], a1 = aabb[1], a2 = aabb[2];
    const float ib0 = 1.f / (aabb[3] - a0 + 1e-5f);
    const float ib1 = 1.f / (aabb[4] - a1 + 1e-5f);
    const float ib2 = 1.f / (aabb[5] - a2 + 1e-5f);

    const SampPos A = load_pos(iA, t_starts, t_ends, rays_o, rays_d, ray_indices,
                               a0, a1, a2, ib0, ib1, ib2);
    const SampPos B = load_pos(iB, t_starts, t_ends, rays_o, rays_d, ray_indices,
                               a0, a1, a2, ib0, ib1, ib2);

    union { _Float16 h[32]; uint4v q[4]; } evA, evB;

    #pragma unroll
    for (int l = 0; l < NLEV; ++l) {
        const float resf = rp.resf[l];
        const _Float16* __restrict__ tab = tabh + (size_t)l * (size_t)(TBL * 2u);

        // ---- sample A setup ----
        const float pA0 = A.x0*resf, pA1 = A.x1*resf, pA2 = A.x2*resf;
        const float flA0 = floorf(pA0), flA1 = floorf(pA1), flA2 = floorf(pA2);
        const float fA0 = pA0-flA0, fA1 = pA1-flA1, fA2 = pA2-flA2;
        const unsigned iA0 = (unsigned)flA0, iA1 = (unsigned)flA1, iA2 = (unsigned)flA2;
        const unsigned hAy0 = iA1 * 2654435761u, hAy1 = hAy0 + 2654435761u;
        const unsigned hAz0 = iA2 * 805459861u,  hAz1 = hAz0 + 805459861u;
        const float gA0 = 1.f-fA0, gA1 = 1.f-fA1, gA2 = 1.f-fA2;
        const unsigned ryzA[4] = { hAy0^hAz0, hAy0^hAz1, hAy1^hAz0, hAy1^hAz1 };
        const float    wyzA[4] = { gA1*gA2,   gA1*fA2,   fA1*gA2,   fA1*fA2 };

        // ---- sample B setup ----
        const float pB0 = B.x0*resf, pB1 = B.x1*resf, pB2 = B.x2*resf;
        const float flB0 = floorf(pB0), flB1 = floorf(pB1), flB2 = floorf(pB2);
        const float fB0 = pB0-flB0, fB1 = pB1-flB1, fB2 = pB2-flB2;
        const unsigned iB0 = (unsigned)flB0, iB1 = (unsigned)flB1, iB2 = (unsigned)flB2;
        const unsigned hBy0 = iB1 * 2654435761u, hBy1 = hBy0 + 2654435761u;
        const unsigned hBz0 = iB2 * 805459861u,  hBz1 = hBz0 + 805459861u;
        const float gB0 = 1.f-fB0, gB1 = 1.f-fB1, gB2 = 1.f-fB2;
        const unsigned ryzB[4] = { hBy0^hBz0, hBy0^hBz1, hBy1^hBz0, hBy1^hBz1 };
        const float    wyzB[4] = { gB1*gB2,   gB1*fB2,   fB1*gB2,   fB1*fB2 };

        unsigned vA0[4], vA1[4], vB0[4], vB1[4];
        corner_gather(tab, iA0, ryzA, vA0, vA1);
        corner_gather(tab, iB0, ryzB, vB0, vB1);

        float eA0 = 0.f, eA1 = 0.f, eB0 = 0.f, eB1 = 0.f;
        #pragma unroll
        for (int c = 0; c < 4; ++c) {
            const float wAlo = gA0 * wyzA[c], wAhi = fA0 * wyzA[c];
            const float2 ta0 = unpack_h2(vA0[c]), ta1 = unpack_h2(vA1[c]);
            eA0 += wAlo * ta0.x + wAhi * ta1.x;
            eA1 += wAlo * ta0.y + wAhi * ta1.y;
            const float wBlo = gB0 * wyzB[c], wBhi = fB0 * wyzB[c];
            const float2 tb0 = unpack_h2(vB0[c]), tb1 = unpack_h2(vB1[c]);
            eB0 += wBlo * tb0.x + wBhi * tb1.x;
            eB1 += wBlo * tb0.y + wBhi * tb1.y;
        }
        evA.h[2*l]   = (_Float16)(eA0 * 1024.f);   // *1024: f16-normal range
        evA.h[2*l+1] = (_Float16)(eA1 * 1024.f);
        evB.h[2*l]   = (_Float16)(eB0 * 1024.f);
        evB.h[2*l+1] = (_Float16)(eB1 * 1024.f);
    }

    uint4v* dstA = (uint4v*)(encG + (size_t)iA * 32);
    #pragma unroll
    for (int q = 0; q < 4; ++q) __builtin_nontemporal_store(evA.q[q], dstA + q);
    if (hasB) {
        uint4v* dstB = (uint4v*)(encG + (size_t)iB * 32);
        #pragma unroll
        for (int q = 0; q < 4; ++q) __builtin_nontemporal_store(evB.q[q], dstB + q);
    }
}

// ---------------------------------------------------------------------------
// Kernel 2: fused MLP, all five layers via MFMA (incl. 64->3 head_w2).
// Block = 256 samples = 4 waves; one barrier. gfx950 16x16x32 layouts:
// A[m=lane&15][k=quad*8+j], B[k][n=lane&15], D: row=quad*4+reg, col=lane&15.
// ---------------------------------------------------------------------------
__global__ __launch_bounds__(256) void k_mlp(
    const float* __restrict__ t_starts, const float* __restrict__ t_ends,
    const float* __restrict__ rays_o,   const float* __restrict__ rays_d,
    const int*   __restrict__ ray_indices,
    const float* __restrict__ bw0,  // [32,64]
    const float* __restrict__ bw1,  // [64,16]
    const float* __restrict__ hw0,  // [31,64]
    const float* __restrict__ hw1,  // [64,64]
    const float* __restrict__ hw2,  // [64,3]
    const float* __restrict__ aabb,
    const _Float16* __restrict__ encG,
    float4* __restrict__ srgb, int n)
{
    __shared__ _Float16 sT  [4][16 * 72];   // per-wave activation transpose buf
    __shared__ _Float16 sSH [256 * 16];
    __shared__ _Float16 sHB [256 * 16];     // h[1..15] + zero col 15
    __shared__ _Float16 sW0T[64 * 40];      // hw0^T, K 31->32 pad
    __shared__ _Float16 sW1T[64 * 64];      // hw1^T[n][k], swizzled
    __shared__ _Float16 sBW0T[64 * 32];     // bw0^T
    __shared__ _Float16 sBW1T[16 * 64];     // bw1^T, swizzled
    __shared__ float    sDT [256];

    const int t     = threadIdx.x;
    const int gbase = blockIdx.x * 256;

    {
        const int s  = gbase + t;            // n % 256 == 0
        const int ri = ray_indices[s];
        const float ts = t_starts[s], te = t_ends[s];
        const float tmid = 0.5f * (ts + te);
        const float ox = rays_o[ri*3+0], oy = rays_o[ri*3+1], oz = rays_o[ri*3+2];
        const float dx = rays_d[ri*3+0], dy = rays_d[ri*3+1], dz = rays_d[ri*3+2];
        const float a0 = aabb[0], a1 = aabb[1], a2c = aabb[2];
        const float b0 = aabb[3], b1 = aabb[4], b2c = aabb[5];
        const float xn0 = (ox + dx*tmid - a0) / (b0 - a0 + 1e-5f);
        const float xn1 = (oy + dy*tmid - a1) / (b1 - a1 + 1e-5f);
        const float xn2 = (oz + dz*tmid - a2c) / (b2c - a2c + 1e-5f);
        const bool sel = (xn0 > 0.f) && (xn0 < 1.f) && (xn1 > 0.f) && (xn1 < 1.f)
                      && (xn2 > 0.f) && (xn2 < 1.f);
        sDT[t] = sel ? (te - ts) : 0.f;

        const float x = dx, y = dy, z = dz;
        const float x2 = x*x, y2 = y*y, z2 = z*z;
        const float xy = x*y, yz = y*z, xz = x*z;
        float shv[16];
        shv[0]  = 0.28209479177387814f;
        shv[1]  = -0.48860251190291987f * y;
        shv[2]  = 0.48860251190291987f * z;
        shv[3]  = -0.48860251190291987f * x;
        shv[4]  = 1.0925484305920792f * xy;
        shv[5]  = -1.0925484305920792f * yz;
        shv[6]  = 0.94617469575756f * z2 - 0.31539156525252005f;
        shv[7]  = -1.0925484305920792f * xz;
        shv[8]  = 0.5462742152960396f * (x2 - y2);
        shv[9]  = -0.5900435899266435f * y * (3.f*x2 - y2);
        shv[10] = 2.890611442640554f * xy * z;
        shv[11] = -0.4570457994644658f * y * (4.f*z2 - x2 - y2);
        shv[12] = 0.3731763325901154f * z * (2.f*z2 - 3.f*x2 - 3.f*y2);
        shv[13] = -0.4570457994644658f * x * (4.f*z2 - x2 - y2);
        shv[14] = 1.445305721320277f * z * (x2 - y2);
        shv[15] = -0.5900435899266435f * x * (x2 - 3.f*y2);
        #pragma unroll
        for (int k4 = 0; k4 < 4; ++k4) {
            half4 p;
            #pragma unroll
            for (int j = 0; j < 4; ++j) p[j] = (_Float16)shv[k4*4 + j];
            *(half4*)&sSH[t*16 + k4*4] = p;
        }
    }
    {
        const int nidx = t & 63, g = t >> 6;
        #pragma unroll
        for (int i2 = 0; i2 < 8; ++i2) {
            const int k = g*8 + i2;
            const float v = (k < 31) ? hw0[k*64 + nidx] : 0.f;
            sW0T[nidx*40 + k] = (_Float16)v;
        }
        #pragma unroll
        for (int i2 = 0; i2 < 16; ++i2) {
            const int k = g*16 + i2;
            sW1T[swz64(nidx, k)] = (_Float16)hw1[k*64 + nidx];
        }
        #pragma unroll
        for (int i2 = 0; i2 < 8; ++i2) {
            const int k = g*8 + i2;
            sBW0T[nidx*32 + k] = (_Float16)bw0[k*64 + nidx];
        }
    }
    {
        const int nidx = t & 15, g = t >> 4;
        #pragma unroll
        for (int i2 = 0; i2 < 4; ++i2) {
            const int k = g*4 + i2;
            sBW1T[swz16(nidx, k)] = (_Float16)bw1[k*16 + nidx];
        }
    }

    const int lane = t & 63, w = t >> 6;
    const int nn = lane & 15, quad = lane >> 4;
    _Float16* myT = &sT[w][0];

    // hw2 B-frag in registers (cols 0..2 = rgb, rest zero)
    half8 BH2[2];
    #pragma unroll
    for (int ks = 0; ks < 2; ++ks)
        #pragma unroll
        for (int j = 0; j < 8; ++j) {
            const int k = ks*32 + quad*8 + j;
            BH2[ks][j] = (nn < 3) ? (_Float16)hw2[k*3 + nn] : (_Float16)0.f;
        }

    __syncthreads();

    const int rbase = w * 64;

    #pragma unroll
    for (int rt = 0; rt < 4; ++rt) {
        const int srow = rbase + rt*16;
        const int drow = srow + quad*4;

        // ---- GEMM1 (transposed): hid^T = bw0^T @ enc^T ----
        half8 bE = *(const half8*)(encG + (size_t)(gbase + srow + nn)*32 + quad*8);
        #pragma unroll
        for (int ct = 0; ct < 4; ++ct) {
            half8 aW = *(const half8*)&sBW0T[(ct*16 + nn)*32 + quad*8];
            floatx4 acc = {0.f, 0.f, 0.f, 0.f};
            acc = __builtin_amdgcn_mfma_f32_16x16x32_f16(aW, bE, acc, 0, 0, 0);
            half4 p;
            #pragma unroll
            for (int r2 = 0; r2 < 4; ++r2) p[r2] = (_Float16)fmaxf(acc[r2], 0.f);
            *(half4*)&myT[nn*72 + ct*16 + quad*4] = p;   // [sample][hid]
        }

        // ---- GEMM2: h = hid @ bw1; sigma broadcast to all lanes ----
        float sigr[4];
        {
            half8 a20 = *(const half8*)&myT[nn*72 +  0 + quad*8];
            half8 a21 = *(const half8*)&myT[nn*72 + 32 + quad*8];
            half8 b20 = *(const half8*)&sBW1T[swz16_blk(nn, quad)];
            half8 b21 = *(const half8*)&sBW1T[swz16_blk(nn, 4 + quad)];
            floatx4 acc = {0.f, 0.f, 0.f, 0.f};
            acc = __builtin_amdgcn_mfma_f32_16x16x32_f16(a20, b20, acc, 0, 0, 0);
            acc = __builtin_amdgcn_mfma_f32_16x16x32_f16(a21, b21, acc, 0, 0, 0);
            #pragma unroll
            for (int r2 = 0; r2 < 4; ++r2) {
                const float h = acc[r2] * (1.f / 1024.f);   // undo enc scale
                const float h0 = __shfl(h, lane & 0x30, 64); // col nn==0 of quad
                sigr[r2] = __expf(h0 - 1.f) * sDT[drow + r2];
                if (nn == 0) sHB[(drow + r2)*16 + 15] = (_Float16)0.f;
                else         sHB[(drow + r2)*16 + (nn - 1)] = (_Float16)h;
            }
        }

        // ---- GEMM3 (transposed): a2^T = hw0^T @ hh^T ----
        half8 shf = *(const half8*)&sSH[(srow + nn)*16 + (quad & 1)*8];
        half8 hbf = *(const half8*)&sHB[(srow + nn)*16 + (quad & 1)*8];
        half8 a3f = (quad < 2) ? shf : hbf;
        #pragma unroll
        for (int ct = 0; ct < 4; ++ct) {
            half8 aW = *(const half8*)&sW0T[(ct*16 + nn)*40 + quad*8];
            floatx4 acc = {0.f, 0.f, 0.f, 0.f};
            acc = __builtin_amdgcn_mfma_f32_16x16x32_f16(aW, a3f, acc, 0, 0, 0);
            half4 p;
            #pragma unroll
            for (int r2 = 0; r2 < 4; ++r2) p[r2] = (_Float16)fmaxf(acc[r2], 0.f);
            *(half4*)&myT[nn*72 + ct*16 + quad*4] = p;   // [sample][a2]
        }

        // ---- GEMM4 (transposed): a3^T = hw1^T @ a2^T; packed writeback ----
        half8 af0 = *(const half8*)&myT[nn*72 +  0 + quad*8];   // a2 B-frag
        half8 af1 = *(const half8*)&myT[nn*72 + 32 + quad*8];
        #pragma unroll
        for (int ct = 0; ct < 4; ++ct) {
            half8 aW0 = *(const half8*)&sW1T[swz64_blk(ct*16 + nn, quad)];
            half8 aW1 = *(const half8*)&sW1T[swz64_blk(ct*16 + nn, 4 + quad)];
            floatx4 acc = {0.f, 0.f, 0.f, 0.f};
            acc = __builtin_amdgcn_mfma_f32_16x16x32_f16(aW0, af0, acc, 0, 0, 0);
            acc = __builtin_amdgcn_mfma_f32_16x16x32_f16(aW1, af1, acc, 0, 0, 0);
            half4 p;
            #pragma unroll
            for (int r2 = 0; r2 < 4; ++r2) p[r2] = (_Float16)fmaxf(acc[r2], 0.f);
            *(half4*)&myT[nn*72 + ct*16 + quad*4] = p;   // [sample][a3]
        }

        // ---- GEMM5: rgb = a3 @ hw2 (cols 0..2); lanes 0..2 write rgb ----
        {
            half8 a50 = *(const half8*)&myT[nn*72 +  0 + quad*8];
            half8 a51 = *(const half8*)&myT[nn*72 + 32 + quad*8];
            floatx4 acc = {0.f, 0.f, 0.f, 0.f};
            acc = __builtin_amdgcn_mfma_f32_16x16x32_f16(a50, BH2[0], acc, 0, 0, 0);
            acc = __builtin_amdgcn_mfma_f32_16x16x32_f16(a51, BH2[1], acc, 0, 0, 0);
            #pragma unroll
            for (int r2 = 0; r2 < 4; ++r2) {
                float* bp = (float*)&srgb[gbase + drow + r2];
                if (nn < 3)       bp[1 + nn] = sigmoidf(acc[r2]);
                else if (nn == 3) bp[0]      = sigr[r2];
            }
        }
    }
}

// ---------------------------------------------------------------------------
// Kernel 3: wave-per-ray compositing with shfl prefix scan.
// ---------------------------------------------------------------------------
__global__ __launch_bounds__(256) void k_render(
    const float* __restrict__ t_starts, const float* __restrict__ t_ends,
    const int*   __restrict__ ray_indices,
    const float4* __restrict__ srgb,
    float* __restrict__ out, int n_samples, int n_rays)
{
    const int wid  = (blockIdx.x * 256 + threadIdx.x) >> 6;
    const int lane = threadIdx.x & 63;
    if (wid >= n_rays) return;
    const int r = wid;

    int lo = 0, hi = n_samples;
    while (lo < hi) { int mid = (lo + hi) >> 1; if (ray_indices[mid] <  r) lo = mid + 1; else hi = mid; }
    const int start = lo;
    hi = n_samples;
    while (lo < hi) { int mid = (lo + hi) >> 1; if (ray_indices[mid] <= r) lo = mid + 1; else hi = mid; }
    const int end = lo;

    float S = 0.f, cr = 0.f, cg = 0.f, cb = 0.f, op = 0.f, dw = 0.f;
    for (int j0 = start; j0 < end; j0 += 64) {
        const int j = j0 + lane;
        float s = 0.f, R = 0.f, G = 0.f, B = 0.f, tm = 0.f;
        if (j < end) {
            const float4 v = srgb[j];
            s = v.x; R = v.y; G = v.z; B = v.w;
            tm = 0.5f * (t_starts[j] + t_ends[j]);
        }
        float incl = s;
        #pragma unroll
        for (int off = 1; off < 64; off <<= 1) {
            const float tv = __shfl_up(incl, off, 64);
            if (lane >= off) incl += tv;
        }
        const float excl  = incl - s;
        const float trans = __expf(-(S + excl));
        const float alpha = 1.f - __expf(-s);
        const float wgt   = trans * alpha;
        cr += wgt * R; cg += wgt * G; cb += wgt * B;
        op += wgt;     dw += wgt * tm;
        S += __shfl(incl, 63, 64);
    }
    #pragma unroll
    for (int off = 1; off < 64; off <<= 1) {
        cr += __shfl_xor(cr, off, 64);
        cg += __shfl_xor(cg, off, 64);
        cb += __shfl_xor(cb, off, 64);
        op += __shfl_xor(op, off, 64);
        dw += __shfl_xor(dw, off, 64);
    }
    if (lane == 0) {
        out[r*3 + 0] = cr;
        out[r*3 + 1] = cg;
        out[r*3 + 2] = cb;
        out[n_rays*3 + r] = op;
        out[n_rays*4 + r] = dw / fmaxf(op, 1.1920929e-7f);
    }
}

// ---------------------------------------------------------------------------
extern "C" void kernel_launch(void* const* d_in, const int* in_sizes, int n_in,
                              void* d_out, int out_size, void* d_ws, size_t ws_size,
                              hipStream_t stream)
{
    const float* t_starts    = (const float*)d_in[0];
    const float* t_ends      = (const float*)d_in[1];
    const float* rays_o      = (const float*)d_in[2];
    const float* rays_d      = (const float*)d_in[3];
    const int*   ray_indices = (const int*)  d_in[4];
    const float* tables      = (const float*)d_in[5];
    const float* bw0         = (const float*)d_in[6];
    const float* bw1         = (const float*)d_in[7];
    const float* hw0         = (const float*)d_in[8];
    const float* hw1         = (const float*)d_in[9];
    const float* hw2         = (const float*)d_in[10];
    const float* aabb        = (const float*)d_in[11];

    const int n      = in_sizes[0];        // 524288
    const int n_rays = in_sizes[2] / 3;    // 8192
    const int tbl_n  = in_sizes[5];        // 16*T*2 floats

    float* out = (float*)d_out;
    char*  ws  = (char*)d_ws;

    const size_t tabh_bytes = (size_t)tbl_n * 2;
    const size_t enc_bytes  = (size_t)n * 64;

    ResParams rp;
    const double scale = exp((log(4096.0) - log(16.0)) / 15.0);
    for (int l = 0; l < NLEV; ++l)
        rp.resf[l] = (float)floor(16.0 * pow(scale, (double)l));

    _Float16* tabh = (_Float16*)ws;
    _Float16* encG = (_Float16*)(ws + tabh_bytes);
    float4*   srgb = (float4*)(ws + tabh_bytes + enc_bytes);

    const int n4 = tbl_n / 4;
    k_cvt<<<(n4 + 255)/256, 256, 0, stream>>>(tables, tabh, n4);

    const int nh = (n + 1) >> 1;
    k_hash2<<<(nh + 255)/256, 256, 0, stream>>>(
        t_starts, t_ends, rays_o, rays_d, ray_indices, tabh, aabb, encG, n, rp);

    k_mlp<<<(n + 255)/256, 256, 0, stream>>>(
        t_starts, t_ends, rays_o, rays_d, ray_indices, bw0, bw1, hw0, hw1, hw2,
        aabb, encG, srgb, n);
    k_render<<<(n_rays*64 + 255)/256, 256, 0, stream>>>(
        t_starts, t_ends, ray_indices, srgb, out, n, n_rays);
}